// Round 7
// baseline (268.124 us; speedup 1.0000x reference)
//
#include <hip/hip_runtime.h>
#include <hip/hip_bf16.h>
#include <cstdint>
#include <cstddef>

#define SEQ_N 2048
#define DIM   1024
#define NHEAD 16
#define DH    64

typedef __bf16 bf16;
typedef __attribute__((ext_vector_type(8))) __bf16 bf16x8;
typedef __attribute__((ext_vector_type(4))) __bf16 bf16x4;
typedef __attribute__((ext_vector_type(4))) float f32x4;

// async global->LDS 16B copy: LDS dest = wave-uniform base + lane*16
__device__ __forceinline__ void gl_lds16(const bf16* g, bf16* l) {
    __builtin_amdgcn_global_load_lds(
        (const __attribute__((address_space(1))) unsigned int*)g,
        (__attribute__((address_space(3))) unsigned int*)l, 16, 0, 0);
}

// ---------------------------------------------------------------------------
// prep: fused input cast (x, pos -> bf16) + all weight transposes.
// ---------------------------------------------------------------------------
__global__ __launch_bounds__(256) void prep_kernel(
    const float* __restrict__ x, const float* __restrict__ pos,
    const float* __restrict__ Wq, const float* __restrict__ Wkv,
    const float* __restrict__ Wo, const float* __restrict__ Wp,
    bf16* __restrict__ xb, bf16* __restrict__ posb,
    bf16* __restrict__ WqkvT, bf16* __restrict__ WoT, bf16* __restrict__ WpT)
{
    int bid = blockIdx.x;
    if (bid < 6144) {
        const int NX = 4096 * 1024;
        int i = (bid * 256 + threadIdx.x) * 4;
        if (i < NX) {
            float4 v = *(const float4*)&x[i];
            xb[i + 0] = (bf16)v.x; xb[i + 1] = (bf16)v.y;
            xb[i + 2] = (bf16)v.z; xb[i + 3] = (bf16)v.w;
        } else {
            int j = i - NX;
            float4 v = *(const float4*)&pos[j];
            posb[j + 0] = (bf16)v.x; posb[j + 1] = (bf16)v.y;
            posb[j + 2] = (bf16)v.z; posb[j + 3] = (bf16)v.w;
        }
        return;
    }
    __shared__ float t[32][33];
    bid -= 6144;
    const float* src; bf16* dst; int tidx, nx, N;
    if (bid < 1024)      { src = Wq;  dst = WqkvT;                       tidx = bid;        nx = 32; N = 1024; }
    else if (bid < 3072) { src = Wkv; dst = WqkvT + (size_t)1024 * 1024; tidx = bid - 1024; nx = 64; N = 2048; }
    else if (bid < 4096) { src = Wo;  dst = WoT;                         tidx = bid - 3072; nx = 32; N = 1024; }
    else                 { src = Wp;  dst = WpT;                         tidx = bid - 4096; nx = 2;  N = 64;   }
    int n0 = (tidx % nx) * 32, k0 = (tidx / nx) * 32;
    int tx = threadIdx.x & 31, ty = threadIdx.x >> 5;
    #pragma unroll
    for (int r = ty; r < 32; r += 8)
        t[r][tx] = src[(size_t)(k0 + r) * N + n0 + tx];
    __syncthreads();
    #pragma unroll
    for (int r = ty; r < 32; r += 8)
        dst[(size_t)(n0 + r) * 1024 + k0 + tx] = (bf16)t[tx][r];
}

// ---------------------------------------------------------------------------
// qkv projection + p projection, one dispatch. grid (25, 32).
// ---------------------------------------------------------------------------
__global__ __launch_bounds__(256) void qkvp_kernel(
    const bf16* __restrict__ xb, const bf16* __restrict__ WqkvT,
    const bf16* __restrict__ posb, const bf16* __restrict__ WpT,
    const float* __restrict__ bq, const float* __restrict__ bkv,
    const float* __restrict__ bp,
    bf16* __restrict__ qbuf, bf16* __restrict__ kbuf,
    bf16* __restrict__ vtbuf, bf16* __restrict__ pfrag)
{
    __shared__ __align__(16) bf16 sm[128 * 132];
    bf16* At = sm;
    bf16* Bt = sm + 128 * 64;
    const int tid = threadIdx.x, w = tid >> 6, lane = tid & 63;
    const int q = lane >> 4, ln15 = lane & 15;
    const int lr = lane >> 3, c_log = (lane & 7) ^ lr;
    const int bx = blockIdx.x, by = blockIdx.y;
    const int m0 = by * 128;

    if (bx == 24) {
        if (by >= 16) return;
        f32x4 acc[2][4] = {};
        for (int k0 = 0; k0 < 1024; k0 += 64) {
            __syncthreads();
            #pragma unroll
            for (int t = 0; t < 4; ++t)
                gl_lds16(&posb[(size_t)(m0 + 32 * w + 8 * t + lr) * 1024 + k0 + c_log * 8],
                         &At[(32 * w + 8 * t) * 64]);
            #pragma unroll
            for (int t = 0; t < 2; ++t)
                gl_lds16(&WpT[(size_t)(16 * w + 8 * t + lr) * 1024 + k0 + c_log * 8],
                         &Bt[(16 * w + 8 * t) * 64]);
            __syncthreads();
            bf16x8 bfr[2][4];
            #pragma unroll
            for (int ks = 0; ks < 2; ++ks)
                #pragma unroll
                for (int sn = 0; sn < 4; ++sn) {
                    int rb = 16 * sn + ln15;
                    bfr[ks][sn] = *(const bf16x8*)&Bt[(rb * 8 + ((4 * ks + q) ^ (rb & 7))) * 8];
                }
            #pragma unroll
            for (int sm2 = 0; sm2 < 2; ++sm2) {
                int ra = 32 * w + 16 * sm2 + ln15;
                #pragma unroll
                for (int ks = 0; ks < 2; ++ks) {
                    bf16x8 af = *(const bf16x8*)&At[(ra * 8 + ((4 * ks + q) ^ (ra & 7))) * 8];
                    #pragma unroll
                    for (int sn = 0; sn < 4; ++sn)
                        acc[sm2][sn] = __builtin_amdgcn_mfma_f32_16x16x32_bf16(
                            af, bfr[ks][sn], acc[sm2][sn], 0, 0, 0);
                }
            }
        }
        #pragma unroll
        for (int sm2 = 0; sm2 < 2; ++sm2)
            #pragma unroll
            for (int sn = 0; sn < 4; ++sn)
                #pragma unroll
                for (int r = 0; r < 4; ++r) {
                    int row = m0 + 32 * w + 16 * sm2 + 4 * q + r;
                    int d = 16 * sn + ln15;
                    int sb = row >> 4, lnp = row & 15;
                    int ks2 = d >> 5, qd = (d >> 3) & 3, e = d & 7;
                    pfrag[(((size_t)sb * 2 + ks2) * 64 + qd * 16 + lnp) * 8 + e] =
                        (bf16)(acc[sm2][sn][r] + bp[d]);
                }
        return;
    }

    const int n0 = bx * 128;
    const int wm = w >> 1, wn = w & 1;
    f32x4 acc[4][4] = {};

    for (int k0 = 0; k0 < 1024; k0 += 64) {
        __syncthreads();
        #pragma unroll
        for (int t = 0; t < 4; ++t) {
            int r = 32 * w + 8 * t + lr;
            gl_lds16(&xb[(size_t)(m0 + r) * 1024 + k0 + c_log * 8],
                     &At[(32 * w + 8 * t) * 64]);
            gl_lds16(&WqkvT[(size_t)(n0 + r) * 1024 + k0 + c_log * 8],
                     &Bt[(32 * w + 8 * t) * 64]);
        }
        __syncthreads();

        bf16x8 af[2][4], bfr[2][4];
        #pragma unroll
        for (int ks = 0; ks < 2; ++ks)
            #pragma unroll
            for (int s = 0; s < 4; ++s) {
                int ra = 64 * wm + 16 * s + ln15;
                af[ks][s]  = *(const bf16x8*)&At[(ra * 8 + ((4 * ks + q) ^ (ra & 7))) * 8];
                int rb = 64 * wn + 16 * s + ln15;
                bfr[ks][s] = *(const bf16x8*)&Bt[(rb * 8 + ((4 * ks + q) ^ (rb & 7))) * 8];
            }
        #pragma unroll
        for (int ks = 0; ks < 2; ++ks)
            #pragma unroll
            for (int si = 0; si < 4; ++si)
                #pragma unroll
                for (int sj = 0; sj < 4; ++sj)
                    acc[si][sj] = __builtin_amdgcn_mfma_f32_16x16x32_bf16(
                        af[ks][si], bfr[ks][sj], acc[si][sj], 0, 0, 0);
    }

    if (bx < 16) {
        #pragma unroll
        for (int si = 0; si < 4; ++si)
            #pragma unroll
            for (int sj = 0; sj < 4; ++sj)
                #pragma unroll
                for (int r = 0; r < 4; ++r) {
                    int row = m0 + 64 * wm + 16 * si + 4 * q + r;
                    int col = n0 + 64 * wn + 16 * sj + ln15;
                    float v = acc[si][sj][r] + (col < 1024 ? bq[col] : bkv[col - 1024]);
                    if (col < 1024) qbuf[(size_t)row * 1024 + col] = (bf16)v;
                    else            kbuf[(size_t)row * 1024 + (col - 1024)] = (bf16)v;
                }
    } else {
        __syncthreads();
        #pragma unroll
        for (int si = 0; si < 4; ++si)
            #pragma unroll
            for (int sj = 0; sj < 4; ++sj) {
                int dL = 64 * wn + 16 * sj + ln15;
                int tL = 64 * wm + 16 * si + 4 * q;
                float bias = bkv[1024 + (bx - 16) * 128 + dL];
                bf16x4 o4;
                #pragma unroll
                for (int r = 0; r < 4; ++r)
                    o4[r] = (bf16)(acc[si][sj][r] + bias);
                *(bf16x4*)&sm[dL * 132 + tL] = o4;
            }
        __syncthreads();
        const int b = m0 >> 11;
        const int t0 = m0 & 2047;
        const int h0 = (bx - 16) * 2;
        #pragma unroll
        for (int p = 0; p < 16; ++p) {
            int d = (tid >> 5) + 8 * p;
            int t = (tid & 31) * 4;
            bf16x4 v4 = *(const bf16x4*)&sm[d * 132 + t];
            int rowv = (b * NHEAD + h0 + (d >> 6)) * DH + (d & 63);
            *(bf16x4*)&vtbuf[(size_t)rowv * SEQ_N + t0 + t] = v4;
        }
    }
}

// ---------------------------------------------------------------------------
// MFMA flash attention, Br=128 (4 waves x 2 adjacent 16-row strips).
// S^T = K.Q^T per strip (stats at lane=i); O^T = V^T.P^T; K/V fragment
// reads shared across both strips; band (rel-shift bias) via per-strip
// register S2 ring (5 subtiles, 4 recomputed/iter; union loads = 5 pairs);
// packed b64 LDS spills. Balance: qb = bi ? 15-bx : bx (pairs sum 34/CU).
// ---------------------------------------------------------------------------
__global__ __launch_bounds__(256, 2) void attn_mfma_kernel(
    const bf16* __restrict__ qp,    // [4096][1024]
    const bf16* __restrict__ kb,    // [4096][1024]
    const bf16* __restrict__ vt,    // [(b,h,d)][2048]
    const bf16* __restrict__ pfrag, // fragment-ready p
    bf16* __restrict__ ob)          // [4096][1024]
{
    const int by = blockIdx.y;
    const int bi = by >> 4, hh = by & 15;
    const int qb = (by >> 4) ? (15 - (int)blockIdx.x) : (int)blockIdx.x;
    const int i0 = qb << 7;
    const int tid = threadIdx.x, w = tid >> 6, lane = tid & 63;
    const int q = lane >> 4, ln15 = lane & 15;
    const int lr = lane >> 3, c_log = (lane & 7) ^ lr;

    // smem (bf16 elems): S2L [0,10752) (8 strips x 16x84; [0,8192) doubles
    // as 128x64 Q staging) ; Ks [10752,14848) ; Vs [14848,18944) ;
    // Pw [18944,27136) (8 strips x 16x64)
    __shared__ __align__(16) bf16 smem[27136];
    bf16* Qs = smem;
    bf16* Ks = smem + 10752;
    bf16* Vs = smem + 14848;
    const int st0 = 2 * w, st1 = 2 * w + 1;
    bf16* S2L0 = smem + st0 * 1344;
    bf16* S2L1 = smem + st1 * 1344;
    bf16* Pw0  = smem + 18944 + st0 * 1024;
    bf16* Pw1  = smem + 18944 + st1 * 1024;

    const bf16* qbase = qp + ((size_t)(bi * SEQ_N + i0)) * DIM + hh * DH;
    const bf16* kbase = kb + ((size_t)bi * SEQ_N) * DIM + hh * DH;
    const bf16* vbase = vt + ((size_t)(bi * NHEAD + hh) * DH) * SEQ_N;

    // stage 128 Q rows (wave w stages and reads ONLY rows 32w..32w+31)
    #pragma unroll
    for (int t = 0; t < 4; ++t)
        gl_lds16(qbase + (size_t)(32 * w + 8 * t + lr) * DIM + c_log * 8,
                 &Qs[(32 * w + 8 * t) * 64]);
    __builtin_amdgcn_s_waitcnt(0);   // own-wave staging complete

    bf16x8 qfA[2], qfB[2];
    {
        int rq = 16 * st0 + ln15;
        qfA[0] = *(const bf16x8*)&Qs[(rq * 8 + ((q    ) ^ (rq & 7))) * 8];
        qfA[1] = *(const bf16x8*)&Qs[(rq * 8 + ((4 + q) ^ (rq & 7))) * 8];
        rq = 16 * st1 + ln15;
        qfB[0] = *(const bf16x8*)&Qs[(rq * 8 + ((q    ) ^ (rq & 7))) * 8];
        qfB[1] = *(const bf16x8*)&Qs[(rq * 8 + ((4 + q) ^ (rq & 7))) * 8];
    }

    const int A0 = 127 - 8 * qb - st0;   // strip0 ring base; strip1 = A0-1
    f32x4 carryA, carryB;
    {
        const bf16* p0 = pfrag + ((size_t)A0 * 128 + lane) * 8;
        bf16x8 f0 = *(const bf16x8*)p0;
        bf16x8 f1 = *(const bf16x8*)(p0 + 512);
        f32x4 a = {0.f, 0.f, 0.f, 0.f};
        a = __builtin_amdgcn_mfma_f32_16x16x32_bf16(f0, qfA[0], a, 0, 0, 0);
        a = __builtin_amdgcn_mfma_f32_16x16x32_bf16(f1, qfA[1], a, 0, 0, 0);
        carryA = a;
        const bf16* p1 = pfrag + ((size_t)(A0 - 1) * 128 + lane) * 8;
        bf16x8 g0 = *(const bf16x8*)p1;
        bf16x8 g1 = *(const bf16x8*)(p1 + 512);
        f32x4 b = {0.f, 0.f, 0.f, 0.f};
        b = __builtin_amdgcn_mfma_f32_16x16x32_bf16(g0, qfB[0], b, 0, 0, 0);
        b = __builtin_amdgcn_mfma_f32_16x16x32_bf16(g1, qfB[1], b, 0, 0, 0);
        carryB = b;
    }
    __syncthreads();   // all qf extracted; S2L (overlapping Qs) now writable

    float mA = -1e30f, lA = 0.f, mB = -1e30f, lB = 0.f;
    f32x4 OA[4] = {}, OB[4] = {};

    const int jtMax = 2 * qb + 1;
    for (int jt = 0; jt <= jtMax; ++jt) {
        const int j0 = jt << 6;
        const bool skipAll = (j0 > i0 + 16 * st1 + 15);   // wave-uniform
        const bool maskA = (j0 + 63) > (i0 + 16 * st0);
        const bool maskB = (j0 + 63) > (i0 + 16 * st1);

        // stage K/V tiles (always: other waves need our rows)
        #pragma unroll
        for (int t = 0; t < 2; ++t) {
            int r = 16 * w + 8 * t + lr;
            gl_lds16(kbase + (size_t)(j0 + r) * DIM + c_log * 8,
                     &Ks[(16 * w + 8 * t) * 64]);
            gl_lds16(vbase + (size_t)r * SEQ_N + j0 + c_log * 8,
                     &Vs[(16 * w + 8 * t) * 64]);
        }

        if (!skipAll) {
            // union band fragments: subtiles A0+4jt+{0..4}
            bf16x8 pfU[5][2];
            #pragma unroll
            for (int s = 0; s < 5; ++s) {
                int sb = A0 + 4 * jt + s;
                if (sb > 127) sb = 127;   // masked region anyway
                const bf16* p = pfrag + ((size_t)sb * 128 + lane) * 8;
                pfU[s][0] = *(const bf16x8*)p;
                pfU[s][1] = *(const bf16x8*)(p + 512);
            }
            // S2 rings (strip0 uses pfU[1..4], strip1 uses pfU[0..3])
            f32x4 rA[5], rB[5];
            rA[0] = carryA; rB[0] = carryB;
            #pragma unroll
            for (int s = 1; s <= 4; ++s) {
                f32x4 a = {0.f, 0.f, 0.f, 0.f};
                a = __builtin_amdgcn_mfma_f32_16x16x32_bf16(pfU[s][0], qfA[0], a, 0, 0, 0);
                a = __builtin_amdgcn_mfma_f32_16x16x32_bf16(pfU[s][1], qfA[1], a, 0, 0, 0);
                rA[s] = a;
                f32x4 b = {0.f, 0.f, 0.f, 0.f};
                b = __builtin_amdgcn_mfma_f32_16x16x32_bf16(pfU[s-1][0], qfB[0], b, 0, 0, 0);
                b = __builtin_amdgcn_mfma_f32_16x16x32_bf16(pfU[s-1][1], qfB[1], b, 0, 0, 0);
                rB[s] = b;
            }
            carryA = rA[4]; carryB = rB[4];
            // packed b64 spills: S2L[i=ln15][16s+4q+0..3]
            #pragma unroll
            for (int s = 0; s < 5; ++s) {
                bf16x4 pkA, pkB;
                #pragma unroll
                for (int r = 0; r < 4; ++r) { pkA[r] = (bf16)rA[s][r]; pkB[r] = (bf16)rB[s][r]; }
                *(bf16x4*)&S2L0[ln15 * 84 + 16 * s + 4 * q] = pkA;
                *(bf16x4*)&S2L1[ln15 * 84 + 16 * s + 4 * q] = pkB;
            }
        }
        __syncthreads();   // K/V staged + spills visible

        if (!skipAll) {
            // S1^T = K.Q^T, shared K fragments
            f32x4 s1A[4], s1B[4];
            #pragma unroll
            for (int sn = 0; sn < 4; ++sn) {
                int rk = 16 * sn + ln15;
                bf16x8 k0f = *(const bf16x8*)&Ks[(rk * 8 + ((q    ) ^ (rk & 7))) * 8];
                bf16x8 k1f = *(const bf16x8*)&Ks[(rk * 8 + ((4 + q) ^ (rk & 7))) * 8];
                f32x4 a = {0.f, 0.f, 0.f, 0.f};
                a = __builtin_amdgcn_mfma_f32_16x16x32_bf16(k0f, qfA[0], a, 0, 0, 0);
                a = __builtin_amdgcn_mfma_f32_16x16x32_bf16(k1f, qfA[1], a, 0, 0, 0);
                s1A[sn] = a;
                f32x4 b = {0.f, 0.f, 0.f, 0.f};
                b = __builtin_amdgcn_mfma_f32_16x16x32_bf16(k0f, qfB[0], b, 0, 0, 0);
                b = __builtin_amdgcn_mfma_f32_16x16x32_bf16(k1f, qfB[1], b, 0, 0, 0);
                s1B[sn] = b;
            }

            // bias + scale + mask
            float svA[4][4], svB[4][4];
            const int dA = i0 + 16 * st0 + ln15 - j0;
            const int dB = dA + 16;
            #pragma unroll
            for (int sn = 0; sn < 4; ++sn)
                #pragma unroll
                for (int r = 0; r < 4; ++r) {
                    int jl = 16 * sn + 4 * q + r;
                    float ba = (float)S2L0[ln15 * 84 + 15 - ln15 + jl];
                    float va = (s1A[sn][r] + ba) * 0.125f;
                    if (maskA && jl > dA) va = -1e30f;
                    svA[sn][r] = va;
                    float bb = (float)S2L1[ln15 * 84 + 15 - ln15 + jl];
                    float vb = (s1B[sn][r] + bb) * 0.125f;
                    if (maskB && jl > dB) vb = -1e30f;
                    svB[sn][r] = vb;
                }

            // online softmax per strip (stats at lane=i, replicated in quads)
            float mxA = svA[0][0], mxB = svB[0][0];
            #pragma unroll
            for (int sn = 0; sn < 4; ++sn)
                #pragma unroll
                for (int r = 0; r < 4; ++r) {
                    mxA = fmaxf(mxA, svA[sn][r]);
                    mxB = fmaxf(mxB, svB[sn][r]);
                }
            mxA = fmaxf(mxA, __shfl_xor(mxA, 16)); mxA = fmaxf(mxA, __shfl_xor(mxA, 32));
            mxB = fmaxf(mxB, __shfl_xor(mxB, 16)); mxB = fmaxf(mxB, __shfl_xor(mxB, 32));
            const float mnA = fmaxf(mA, mxA), mnB = fmaxf(mB, mxB);
            float sumA = 0.f, sumB = 0.f;
            #pragma unroll
            for (int sn = 0; sn < 4; ++sn)
                #pragma unroll
                for (int r = 0; r < 4; ++r) {
                    float ea = __expf(svA[sn][r] - mnA); svA[sn][r] = ea; sumA += ea;
                    float eb = __expf(svB[sn][r] - mnB); svB[sn][r] = eb; sumB += eb;
                }
            sumA += __shfl_xor(sumA, 16); sumA += __shfl_xor(sumA, 32);
            sumB += __shfl_xor(sumB, 16); sumB += __shfl_xor(sumB, 32);
            const float alA = __expf(mA - mnA), alB = __expf(mB - mnB);
            lA = lA * alA + sumA; mA = mnA;
            lB = lB * alB + sumB; mB = mnB;

            // P -> per-strip LDS (packed b64, chunk-xor swizzle)
            #pragma unroll
            for (int sn = 0; sn < 4; ++sn) {
                int chunk = (2 * sn + (q >> 1)) ^ (ln15 & 7);
                int off = ln15 * 64 + chunk * 8 + 4 * (q & 1);
                bf16x4 pkA, pkB;
                #pragma unroll
                for (int r = 0; r < 4; ++r) { pkA[r] = (bf16)svA[sn][r]; pkB[r] = (bf16)svB[sn][r]; }
                *(bf16x4*)&Pw0[off] = pkA;
                *(bf16x4*)&Pw1[off] = pkB;
            }
            #pragma unroll
            for (int sd = 0; sd < 4; ++sd)
                #pragma unroll
                for (int r = 0; r < 4; ++r) {
                    OA[sd][r] *= alA;
                    OB[sd][r] *= alB;
                }

            __builtin_amdgcn_s_waitcnt(0);   // Pw stores visible intra-wave

            // O^T += V^T @ P^T (shared V fragments)
            bf16x8 pTA[2], pTB[2];
            #pragma unroll
            for (int ks = 0; ks < 2; ++ks) {
                int off = ln15 * 64 + (((4 * ks + q) ^ (ln15 & 7))) * 8;
                pTA[ks] = *(const bf16x8*)&Pw0[off];
                pTB[ks] = *(const bf16x8*)&Pw1[off];
            }
            #pragma unroll
            for (int ks = 0; ks < 2; ++ks)
                #pragma unroll
                for (int sd = 0; sd < 4; ++sd) {
                    int rv = 16 * sd + ln15;
                    bf16x8 vf = *(const bf16x8*)&Vs[(rv * 8 + ((4 * ks + q) ^ (rv & 7))) * 8];
                    OA[sd] = __builtin_amdgcn_mfma_f32_16x16x32_bf16(vf, pTA[ks], OA[sd], 0, 0, 0);
                    OB[sd] = __builtin_amdgcn_mfma_f32_16x16x32_bf16(vf, pTB[ks], OB[sd], 0, 0, 0);
                }
        }
        __syncthreads();   // Ks/Vs consumed before next staging
    }

    // epilogue: both strips
    {
        const float invA = 1.0f / lA;
        const size_t rowA = (size_t)bi * SEQ_N + i0 + 16 * st0 + ln15;
        #pragma unroll
        for (int sd = 0; sd < 4; ++sd) {
            bf16x4 o4;
            #pragma unroll
            for (int r = 0; r < 4; ++r) o4[r] = (bf16)(OA[sd][r] * invA);
            *(bf16x4*)&ob[rowA * DIM + hh * DH + 16 * sd + 4 * q] = o4;
        }
        const float invB = 1.0f / lB;
        const size_t rowB = (size_t)bi * SEQ_N + i0 + 16 * st1 + ln15;
        #pragma unroll
        for (int sd = 0; sd < 4; ++sd) {
            bf16x4 o4;
            #pragma unroll
            for (int r = 0; r < 4; ++r) o4[r] = (bf16)(OB[sd][r] * invB);
            *(bf16x4*)&ob[rowB * DIM + hh * DH + 16 * sd + 4 * q] = o4;
        }
    }
}

// ---------------------------------------------------------------------------
// out = abuf @ WoT^T + bo, fp32 out. 128x64 tiles -> grid (16,32), 2/CU.
// ---------------------------------------------------------------------------
__global__ __launch_bounds__(256) void outproj_kernel(
    const bf16* __restrict__ ab, const bf16* __restrict__ WoT,
    const float* __restrict__ bo, float* __restrict__ out)
{
    __shared__ __align__(16) bf16 At[128 * 64];
    __shared__ __align__(16) bf16 Bt[64 * 64];
    const int tid = threadIdx.x, w = tid >> 6, lane = tid & 63;
    const int q = lane >> 4, ln15 = lane & 15;
    const int lr = lane >> 3, c_log = (lane & 7) ^ lr;
    const int m0 = blockIdx.y * 128, n0 = blockIdx.x * 64;

    f32x4 acc[2][4] = {};
    for (int k0 = 0; k0 < 1024; k0 += 64) {
        __syncthreads();
        #pragma unroll
        for (int t = 0; t < 4; ++t)
            gl_lds16(&ab[(size_t)(m0 + 32 * w + 8 * t + lr) * 1024 + k0 + c_log * 8],
                     &At[(32 * w + 8 * t) * 64]);
        #pragma unroll
        for (int t = 0; t < 2; ++t)
            gl_lds16(&WoT[(size_t)(n0 + 16 * w + 8 * t + lr) * 1024 + k0 + c_log * 8],
                     &Bt[(16 * w + 8 * t) * 64]);
        __syncthreads();

        bf16x8 bfr[2][4];
        #pragma unroll
        for (int ks = 0; ks < 2; ++ks)
            #pragma unroll
            for (int sn = 0; sn < 4; ++sn) {
                int rb = 16 * sn + ln15;
                bfr[ks][sn] = *(const bf16x8*)&Bt[(rb * 8 + ((4 * ks + q) ^ (rb & 7))) * 8];
            }
        #pragma unroll
        for (int sm2 = 0; sm2 < 2; ++sm2) {
            int ra = 32 * w + 16 * sm2 + ln15;
            #pragma unroll
            for (int ks = 0; ks < 2; ++ks) {
                bf16x8 af = *(const bf16x8*)&At[(ra * 8 + ((4 * ks + q) ^ (ra & 7))) * 8];
                #pragma unroll
                for (int sn = 0; sn < 4; ++sn)
                    acc[sm2][sn] = __builtin_amdgcn_mfma_f32_16x16x32_bf16(
                        af, bfr[ks][sn], acc[sm2][sn], 0, 0, 0);
            }
        }
    }
    #pragma unroll
    for (int sm2 = 0; sm2 < 2; ++sm2)
        #pragma unroll
        for (int sn = 0; sn < 4; ++sn) {
            int col = n0 + 16 * sn + ln15;
            float bias = bo[col];
            #pragma unroll
            for (int r = 0; r < 4; ++r) {
                int row = m0 + 32 * w + 16 * sm2 + 4 * q + r;
                out[(size_t)row * 1024 + col] = acc[sm2][sn][r] + bias;
            }
        }
}

// ---------------------------------------------------------------------------
extern "C" void kernel_launch(void* const* d_in, const int* in_sizes, int n_in,
                              void* d_out, int out_size, void* d_ws, size_t ws_size,
                              hipStream_t stream)
{
    const float* x    = (const float*)d_in[0];
    const float* pos  = (const float*)d_in[1];
    const float* Wq   = (const float*)d_in[2];
    const float* bq   = (const float*)d_in[3];
    const float* Wkv  = (const float*)d_in[4];
    const float* bkv  = (const float*)d_in[5];
    const float* Wp   = (const float*)d_in[6];
    const float* bp   = (const float*)d_in[7];
    const float* Wo   = (const float*)d_in[8];
    const float* bo   = (const float*)d_in[9];
    float* out = (float*)d_out;

    const int M = 2 * SEQ_N;   // 4096
    char* ws = (char*)d_ws;
    bf16* xb     = (bf16*)ws;  ws += (size_t)M * DIM * 2;
    bf16* posb   = (bf16*)ws;  ws += (size_t)SEQ_N * DIM * 2;
    bf16* WqkvT  = (bf16*)ws;  ws += (size_t)3072 * 1024 * 2;
    bf16* WoT    = (bf16*)ws;  ws += (size_t)DIM * DIM * 2;
    bf16* WpT    = (bf16*)ws;  ws += (size_t)DH * DIM * 2;
    bf16* qbuf   = (bf16*)ws;  ws += (size_t)M * DIM * 2;
    bf16* kbuf   = (bf16*)ws;  ws += (size_t)M * DIM * 2;
    bf16* vtbuf  = (bf16*)ws;  ws += (size_t)M * DIM * 2;
    bf16* pfrag  = (bf16*)ws;  ws += (size_t)512 * 1024;
    bf16* abuf   = (bf16*)ws;

    dim3 blk(256);
    prep_kernel<<<dim3(10304), blk, 0, stream>>>(
        x, pos, Wq, Wkv, Wo, Wp, xb, posb, WqkvT, WoT, WpT);

    qkvp_kernel<<<dim3(25, 32), blk, 0, stream>>>(
        xb, WqkvT, posb, WpT, bq, bkv, bp, qbuf, kbuf, vtbuf, pfrag);

    attn_mfma_kernel<<<dim3(16, 32), blk, 0, stream>>>(
        qbuf, kbuf, vtbuf, pfrag, abuf);

    outproj_kernel<<<dim3(16, 32), blk, 0, stream>>>(
        abuf, WoT, bo, out);
}